// Round 2
// baseline (363.593 us; speedup 1.0000x reference)
//
#include <hip/hip_runtime.h>
#include <stdint.h>

// Scatter-upsample with numpy last-write-wins semantics.
//   y = zeros((num_nodes, 256)); y[col(k), row(k)] = x.flat[k]  (k ascending wins)
//   col(k) = neigh[7*i + max_index[i,f]],  k = i*256 + f
//   row(k) = floor(k*256/(total-1))  -> constant over windows of ~40961 k's
//
// DTYPE NOTE (round-1 post-mortem): buffers are float32 words holding
// bf16-rounded values (ref max 4.625 is bf16-clean => ref computed on
// bf16-rounded inputs; round-1 NaN proved the device buffers are 32-bit).
// x: const float*, out: float*, indices: int32.
//
// Structure: each row r is fed by one contiguous k-window spanning ~161
// nodes; each node contributes <=7 distinct cols => <=~1140 distinct targets
// per window (~290K total vs 41.9M output slots, 99.3% zeros).
// One WG per row-window; per-wave ballot keeps only the max-f lane per
// (node,m) chunk (same col, smaller k => dominated); LDS hash keyed by col
// with atomicMax on k resolves all remaining collisions exactly (max k ==
// numpy last-write-wins). Then ~1140 direct float stores.

#define FEAT 256
#define LOG2FEAT 8
#define HASH_BITS 12
#define HASH_SIZE (1 << HASH_BITS)   // 4096 slots for <=~1141 entries (28% load)
#define HASH_MASK (HASH_SIZE - 1)
#define BLOCK 1024

__device__ __forceinline__ void hash_insert(int* h_key, int* h_val, int col, int k) {
    unsigned h = ((unsigned)col * 2654435761u) >> (32 - HASH_BITS);
    for (;;) {
        int cur = h_key[h];
        if (cur == -1) {
            cur = atomicCAS(&h_key[h], -1, col);
            if (cur == -1) cur = col;  // we claimed this slot
        }
        if (cur == col) {
            atomicMax(&h_val[h], k);   // last-write-wins == max k
            return;
        }
        h = (h + 1) & HASH_MASK;       // linear probe
    }
}

extern "C" __global__ __launch_bounds__(BLOCK)
void upsample_window_kernel(const float* __restrict__ x,     // f32 (bf16-rounded values)
                            const int*   __restrict__ mi,    // max_index, int32, 0..6
                            const int*   __restrict__ neigh, // neigh_orders, int32
                            float*       __restrict__ out,   // f32
                            int total)                        // raw_nodes * FEAT
{
    __shared__ int h_key[HASH_SIZE];
    __shared__ int h_val[HASH_SIZE];

    const int r   = blockIdx.x;        // row window, 0..255
    const int tid = threadIdx.x;

    for (int idx = tid; idx < HASH_SIZE; idx += BLOCK) {
        h_key[idx] = -1;
        h_val[idx] = 0;
    }
    __syncthreads();

    // Window r: row(k)==r  <=>  k*256 in [r*(total-1), (r+1)*(total-1))
    const long long tm1 = (long long)total - 1;
    const long long k_lo = ((long long)r * tm1 + (FEAT - 1)) >> LOG2FEAT;
    long long       k_hi = ((long long)(r + 1) * tm1 + (FEAT - 1)) >> LOG2FEAT;
    if (r == FEAT - 1) k_hi = total;   // last element: row clamped 256 -> 255

    const int i_lo = (int)(k_lo >> LOG2FEAT);
    const int i_hi = (int)((k_hi - 1) >> LOG2FEAT);  // inclusive

    const int lane     = tid & 63;
    const int f        = tid & (FEAT - 1);
    const int node_off = tid >> LOG2FEAT;            // 0..3: 4 nodes per iteration

    for (int ibase = i_lo; ibase <= i_hi; ibase += (BLOCK >> LOG2FEAT)) {
        const int i = ibase + node_off;
        const int k = (i << LOG2FEAT) | f;
        const bool valid = (i <= i_hi) && ((long long)k >= k_lo) && ((long long)k < k_hi);
        int m = 7;                                   // 7 == never matches
        if (valid) m = mi[((size_t)i << LOG2FEAT) | (size_t)f];

        // Per-wave: for each m, the highest-f lane in this 64-f chunk is the
        // only live candidate (same node+m => same col; larger k dominates).
        // Cross-chunk/cross-node duplicates resolved in the hash via max-k.
        #pragma unroll
        for (int mm = 0; mm < 7; ++mm) {
            unsigned long long mask = __ballot(m == mm);
            if (mask != 0ull) {
                int top = 63 - __clzll(mask);
                if (lane == top) {
                    int col = neigh[i * 7 + mm];
                    hash_insert(h_key, h_val, col, k);
                }
            }
        }
    }
    __syncthreads();

    // Drain hash: each surviving (col -> max k) is a unique output slot.
    for (int idx = tid; idx < HASH_SIZE; idx += BLOCK) {
        int col = h_key[idx];
        if (col >= 0) {
            int k = h_val[idx];
            out[((size_t)col << LOG2FEAT) + (size_t)r] = x[k];
        }
    }
}

extern "C" void kernel_launch(void* const* d_in, const int* in_sizes, int n_in,
                              void* d_out, int out_size, void* d_ws, size_t ws_size,
                              hipStream_t stream) {
    const float* x     = (const float*)d_in[0];   // f32 (40962, 256)
    const int*   mi    = (const int*)d_in[1];     // int32 (40962, 256), values 0..6
    const int*   neigh = (const int*)d_in[2];     // int32 (40962*7,)
    // d_in[3] = num_nodes scalar — unused (out covers num_nodes*FEAT)
    float* out = (float*)d_out;

    const int total = in_sizes[0];                // raw_nodes * 256

    // Output is ~99.3% zeros: zero it, then scatter the ~290K winners.
    hipMemsetAsync(d_out, 0, (size_t)out_size * sizeof(float), stream);

    dim3 grid(FEAT);     // one workgroup per row window
    dim3 block(BLOCK);
    upsample_window_kernel<<<grid, block, 0, stream>>>(x, mi, neigh, out, total);
}

// Round 3
// 336.286 us; speedup vs baseline: 1.0812x; 1.0812x over previous
//
#include <hip/hip_runtime.h>
#include <hip/hip_cooperative_groups.h>
#include <stdint.h>

namespace cg = cooperative_groups;

// Scatter-upsample, numpy last-write-wins:
//   y = zeros((num_nodes,256)); y[col(k), row(k)] = x.flat[k]  (largest k wins)
//   col(k) = neigh[7*i + max_index[i,f]], k = i*256+f
//   row(k) = floor(k*256/(total-1)) -> one contiguous ~40962-k window per row.
//
// R2 post-mortem: old kernel was 146us, hbm 231 GB/s, VALUBusy 22% -> latency
// bound on the 7x-serialized {divergent global neigh load + LDS CAS} chain.
// Fixes: (a) neigh window slice staged in LDS once; (b) all 7 ballots first,
// then lanes 0..6 insert their mm CONCURRENTLY (one insert-latency per iter,
// not seven, and LDS-latency not global); (c) fuse the 168MB output zeroing
// into the same kernel via cooperative grid.sync (zero -> sync -> drain),
// removing the separate memset dispatch.

#define FEAT 256
#define LOG2FEAT 8
#define HASH_BITS 12
#define HASH_SIZE (1 << HASH_BITS)   // 4096 slots for <=~1141 entries
#define HASH_MASK (HASH_SIZE - 1)
#define BLOCK 1024
#define MAX_WIN_NODES 164            // window spans <= ~162 nodes

__device__ __forceinline__ void hash_insert(int* h_key, int* h_val, int col, int k) {
    unsigned h = ((unsigned)col * 2654435761u) >> (32 - HASH_BITS);
    for (;;) {
        int cur = h_key[h];
        if (cur == -1) {
            cur = atomicCAS(&h_key[h], -1, col);
            if (cur == -1) cur = col;  // we claimed this slot
        }
        if (cur == col) {
            atomicMax(&h_val[h], k);   // last-write-wins == max k
            return;
        }
        h = (h + 1) & HASH_MASK;       // linear probe
    }
}

__global__ void __launch_bounds__(BLOCK)
upsample_fused_kernel(const float* __restrict__ x,     // f32 (bf16-rounded values)
                      const int*   __restrict__ mi,    // max_index int32, 0..6
                      const int*   __restrict__ neigh, // neigh_orders int32
                      float*       __restrict__ out,   // f32, num_nodes*256
                      int total,                        // raw_nodes * 256
                      int out_elems)                    // num_nodes * 256
{
    __shared__ int h_key[HASH_SIZE];
    __shared__ int h_val[HASH_SIZE];
    __shared__ int neigh_lds[MAX_WIN_NODES * 7];

    const int r   = blockIdx.x;        // row window, 0..255
    const int tid = threadIdx.x;

    // Window r: row(k)==r  <=>  k in [ceil(r*tm1/256), ceil((r+1)*tm1/256))
    const long long tm1 = (long long)total - 1;
    const int k_lo = (int)(((long long)r * tm1 + (FEAT - 1)) >> LOG2FEAT);
    int       k_hi = (int)(((long long)(r + 1) * tm1 + (FEAT - 1)) >> LOG2FEAT);
    if (r == FEAT - 1) k_hi = total;   // last element's row clamped 256 -> 255

    const int i_lo = k_lo >> LOG2FEAT;
    const int i_hi = (k_hi - 1) >> LOG2FEAT;          // inclusive
    const int nwin7 = (i_hi - i_lo + 1) * 7;          // <= 162*7

    // --- init hash + stage this window's neigh slice into LDS (coalesced) ---
    for (int idx = tid; idx < HASH_SIZE; idx += BLOCK) {
        h_key[idx] = -1;
        h_val[idx] = 0;
    }
    for (int idx = tid; idx < nwin7; idx += BLOCK)
        neigh_lds[idx] = neigh[i_lo * 7 + idx];
    __syncthreads();

    // --- build phase: one wave handles one node's 64-f chunk per iteration --
    const int lane        = tid & 63;
    const int f           = tid & (FEAT - 1);
    const int wave_f_base = tid & (FEAT - 1) & ~63;   // f of lane 0 in this wave
    const int node_off    = tid >> LOG2FEAT;          // uniform per wave: 0..3

    for (int ibase = i_lo; ibase <= i_hi; ibase += (BLOCK >> LOG2FEAT)) {
        const int i = ibase + node_off;               // uniform per wave
        const int k = (i << LOG2FEAT) | f;
        const bool valid = (i <= i_hi) && (k >= k_lo) && (k < k_hi);
        const int m = valid ? mi[k] : 7;              // 7 == matches nothing

        // All 7 ballots up front (cheap VALU), then 7 CONCURRENT inserts on
        // lanes 0..6 — one LDS-insert latency per iteration instead of seven.
        const unsigned long long b0 = __ballot(m == 0);
        const unsigned long long b1 = __ballot(m == 1);
        const unsigned long long b2 = __ballot(m == 2);
        const unsigned long long b3 = __ballot(m == 3);
        const unsigned long long b4 = __ballot(m == 4);
        const unsigned long long b5 = __ballot(m == 5);
        const unsigned long long b6 = __ballot(m == 6);
        unsigned long long mym =
            (lane == 0) ? b0 : (lane == 1) ? b1 : (lane == 2) ? b2 :
            (lane == 3) ? b3 : (lane == 4) ? b4 : (lane == 5) ? b5 :
            (lane == 6) ? b6 : 0ull;
        if (mym != 0ull) {   // implies lane<7 and wave's node has valid lanes
            const int top  = 63 - __clzll(mym);       // highest-f survivor
            const int k_t  = (i << LOG2FEAT) | (wave_f_base + top);
            const int col  = neigh_lds[(i - i_lo) * 7 + lane];
            hash_insert(h_key, h_val, col, k_t);
        }
    }

    // --- zero phase: grid-stride float4 over the whole output (fused memset)
    float4* out4 = (float4*)out;
    const int total4 = out_elems >> 2;                 // exact multiple of 4
    const float4 z = make_float4(0.f, 0.f, 0.f, 0.f);
    for (int idx = blockIdx.x * BLOCK + tid; idx < total4; idx += gridDim.x * BLOCK)
        out4[idx] = z;

    cg::this_grid().sync();   // all zeroing done before any scatter lands

    // --- drain: each surviving (col -> max k) is a unique output slot -------
    for (int idx = tid; idx < HASH_SIZE; idx += BLOCK) {
        const int col = h_key[idx];
        if (col >= 0)
            out[(size_t)col << LOG2FEAT | (size_t)r] = x[h_val[idx]];
    }
}

extern "C" void kernel_launch(void* const* d_in, const int* in_sizes, int n_in,
                              void* d_out, int out_size, void* d_ws, size_t ws_size,
                              hipStream_t stream) {
    const float* x     = (const float*)d_in[0];   // f32 (40962, 256)
    const int*   mi    = (const int*)d_in[1];     // int32 (40962, 256), 0..6
    const int*   neigh = (const int*)d_in[2];     // int32 (40962*7,)
    float*       out   = (float*)d_out;

    int total     = in_sizes[0];                  // raw_nodes * 256
    int out_elems = out_size;                     // num_nodes * 256

    void* args[] = { (void*)&x, (void*)&mi, (void*)&neigh, (void*)&out,
                     (void*)&total, (void*)&out_elems };
    hipLaunchCooperativeKernel((const void*)upsample_fused_kernel,
                               dim3(FEAT), dim3(BLOCK), args, 0, stream);
}

// Round 4
// 287.613 us; speedup vs baseline: 1.2642x; 1.1692x over previous
//
#include <hip/hip_runtime.h>
#include <stdint.h>

// Scatter-upsample, numpy last-write-wins:
//   y = zeros((num_nodes,256)); y[col(k), row(k)] = x.flat[k]  (largest k wins)
//   col(k) = neigh[7*i + max_index[i,f]], k = i*256+f
//   row(k) = floor(k*256/(total-1)) -> one contiguous ~40962-k window per row.
//
// R3 post-mortem: fused coop kernel 124us at 1.6 TB/s while the harness's own
// fill runs 5.4 TB/s -> we serialized a ~85us latency-bound build phase with a
// ~30us BW-bound zero phase on the same 256 WGs. Fix: role-split grid.
//   Kernel A (grid 1024): WGs 0-255 build one row-window each (LDS hash,
//     mi-load software pipeline, dump compact (col, x-value-bits) to d_ws);
//     WGs 256-1023 zero the 168MB output at full write BW CONCURRENTLY.
//   Kernel B (tiny): scatter the ~290K winners from the compact lists.
// Stream order between A and B is the global barrier (no coop launch).

#define FEAT 256
#define LOG2FEAT 8
#define HASH_BITS 12
#define HASH_SIZE (1 << HASH_BITS)
#define HASH_MASK (HASH_SIZE - 1)
#define BLOCK 1024
#define BUILD_WGS 256
#define ZERO_WGS 768
#define MAX_WIN_NODES 164      // window spans <= ~162 nodes
#define ENTRY_CAP 1152         // >= 162*7 = 1134 max candidates/window
#define ENTRY_BASE_BYTES 4096  // counts[256] live at ws+0; entries after

__device__ __forceinline__ void hash_insert(int* h_key, int* h_val, int col, int k) {
    unsigned h = ((unsigned)col * 2654435761u) >> (32 - HASH_BITS);
    for (;;) {
        int cur = h_key[h];
        if (cur == -1) {
            cur = atomicCAS(&h_key[h], -1, col);
            if (cur == -1) cur = col;  // claimed
        }
        if (cur == col) {
            atomicMax(&h_val[h], k);   // last-write-wins == max k
            return;
        }
        h = (h + 1) & HASH_MASK;
    }
}

extern "C" __global__ __launch_bounds__(BLOCK)
void build_zero_kernel(const float* __restrict__ x,     // f32 (bf16-rounded vals)
                       const int*   __restrict__ mi,    // max_index int32 0..6
                       const int*   __restrict__ neigh, // neigh_orders int32
                       float*       __restrict__ out,   // f32 num_nodes*256
                       int*         __restrict__ ws_counts,   // [256]
                       int2*        __restrict__ ws_entries,  // [256][ENTRY_CAP]
                       int total,                        // raw_nodes*256
                       int out_elems)                    // num_nodes*256
{
    const int tid = threadIdx.x;

    // ---------------- zeroer role: saturate HBM write BW --------------------
    if (blockIdx.x >= BUILD_WGS) {
        const int zid = blockIdx.x - BUILD_WGS;
        float4* out4 = (float4*)out;
        const int total4 = out_elems >> 2;               // exact multiple of 4
        const float4 z = make_float4(0.f, 0.f, 0.f, 0.f);
        for (int idx = zid * BLOCK + tid; idx < total4; idx += ZERO_WGS * BLOCK)
            out4[idx] = z;
        return;
    }

    // ---------------- builder role: one row-window per WG -------------------
    __shared__ int h_key[HASH_SIZE];
    __shared__ int h_val[HASH_SIZE];
    __shared__ int neigh_lds[MAX_WIN_NODES * 7];
    __shared__ int lds_count;

    const int r = blockIdx.x;          // row window, 0..255

    // Window r: row(k)==r  <=>  k in [ceil(r*tm1/256), ceil((r+1)*tm1/256))
    const long long tm1 = (long long)total - 1;
    const int k_lo = (int)(((long long)r * tm1 + (FEAT - 1)) >> LOG2FEAT);
    int       k_hi = (int)(((long long)(r + 1) * tm1 + (FEAT - 1)) >> LOG2FEAT);
    if (r == FEAT - 1) k_hi = total;   // last element's row clamped 256 -> 255

    const int i_lo = k_lo >> LOG2FEAT;
    const int i_hi = (k_hi - 1) >> LOG2FEAT;           // inclusive
    const int nwin7 = (i_hi - i_lo + 1) * 7;

    for (int idx = tid; idx < HASH_SIZE; idx += BLOCK) {
        h_key[idx] = -1;
        h_val[idx] = 0;
    }
    for (int idx = tid; idx < nwin7; idx += BLOCK)
        neigh_lds[idx] = neigh[i_lo * 7 + idx];
    if (tid == 0) lds_count = 0;
    __syncthreads();

    const int lane        = tid & 63;
    const int f           = tid & (FEAT - 1);
    const int wave_f_base = f & ~63;                   // f of lane 0 this wave
    const int node_off    = tid >> LOG2FEAT;           // uniform per wave: 0..3

    // Software-pipelined mi stream: prefetch iter n+1's value before
    // processing iter n, so the global-load latency overlaps ballots+insert.
    int i0 = i_lo + node_off;
    int k0 = (i0 << LOG2FEAT) | f;
    bool v0 = (i0 <= i_hi) && (k0 >= k_lo) && (k0 < k_hi);
    int m_cur = v0 ? mi[k0] : 7;                       // 7 == matches nothing

    for (int ibase = i_lo; ibase <= i_hi; ibase += (BLOCK >> LOG2FEAT)) {
        const int i = ibase + node_off;

        const int ibase_n = ibase + (BLOCK >> LOG2FEAT);
        const int i_n = ibase_n + node_off;
        const int k_n = (i_n << LOG2FEAT) | f;
        const bool v_n = (ibase_n <= i_hi) && (i_n <= i_hi) && (k_n >= k_lo) && (k_n < k_hi);
        const int m_next = v_n ? mi[k_n] : 7;          // issued early, used next iter

        const unsigned long long b0 = __ballot(m_cur == 0);
        const unsigned long long b1 = __ballot(m_cur == 1);
        const unsigned long long b2 = __ballot(m_cur == 2);
        const unsigned long long b3 = __ballot(m_cur == 3);
        const unsigned long long b4 = __ballot(m_cur == 4);
        const unsigned long long b5 = __ballot(m_cur == 5);
        const unsigned long long b6 = __ballot(m_cur == 6);
        unsigned long long mym =
            (lane == 0) ? b0 : (lane == 1) ? b1 : (lane == 2) ? b2 :
            (lane == 3) ? b3 : (lane == 4) ? b4 : (lane == 5) ? b5 :
            (lane == 6) ? b6 : 0ull;
        if (mym != 0ull) {                             // lanes 0..6 concurrent
            const int top = 63 - __clzll(mym);         // highest-f survivor
            const int k_t = (i << LOG2FEAT) | (wave_f_base + top);
            const int col = neigh_lds[(i - i_lo) * 7 + lane];
            hash_insert(h_key, h_val, col, k_t);
        }
        m_cur = m_next;
    }
    __syncthreads();

    // Compact dump: (col, x-value-bits) so the drain never touches x or mi.
    for (int idx = tid; idx < HASH_SIZE; idx += BLOCK) {
        const int col = h_key[idx];
        if (col >= 0) {
            const float v = x[h_val[idx]];             // scattered, ~1134/WG
            const int pos = atomicAdd(&lds_count, 1);
            if (pos < ENTRY_CAP)
                ws_entries[r * ENTRY_CAP + pos] = make_int2(col, __float_as_int(v));
        }
    }
    __syncthreads();
    if (tid == 0) ws_counts[r] = lds_count;
}

extern "C" __global__ __launch_bounds__(256)
void drain_kernel(float* __restrict__ out,
                  const int*  __restrict__ ws_counts,
                  const int2* __restrict__ ws_entries)
{
    const int r = blockIdx.x;
    const int cnt = ws_counts[r];
    for (int idx = threadIdx.x; idx < cnt; idx += 256) {
        const int2 e = ws_entries[r * ENTRY_CAP + idx];
        out[((size_t)e.x << LOG2FEAT) | (size_t)r] = __int_as_float(e.y);
    }
}

extern "C" void kernel_launch(void* const* d_in, const int* in_sizes, int n_in,
                              void* d_out, int out_size, void* d_ws, size_t ws_size,
                              hipStream_t stream) {
    const float* x     = (const float*)d_in[0];   // f32 (40962, 256)
    const int*   mi    = (const int*)d_in[1];     // int32 (40962, 256), 0..6
    const int*   neigh = (const int*)d_in[2];     // int32 (40962*7,)
    float*       out   = (float*)d_out;

    int total     = in_sizes[0];                  // raw_nodes * 256
    int out_elems = out_size;                     // num_nodes * 256

    int*  ws_counts  = (int*)d_ws;
    int2* ws_entries = (int2*)((char*)d_ws + ENTRY_BASE_BYTES);
    // ws usage: 4096 + 256*1152*8 = ~2.4 MB

    build_zero_kernel<<<dim3(BUILD_WGS + ZERO_WGS), dim3(BLOCK), 0, stream>>>(
        x, mi, neigh, out, ws_counts, ws_entries, total, out_elems);
    drain_kernel<<<dim3(FEAT), dim3(256), 0, stream>>>(out, ws_counts, ws_entries);
}